// Round 14
// baseline (324.838 us; speedup 1.0000x reference)
//
#include <hip/hip_runtime.h>

// out[b,c,y,x] = sum_{kdy,kdx in [0,9)} corr[b, kdy*9+kdx, y+4-kdy, x+4-kdx] * feat[b,c, y+4-kdy, x+4-kdx]
// MFMA formulation (R11 numerics): per (b,y,cgh): out[128c, 96x] = sum_kdy A_kdy[C,K] * M_kdy[K,X]
//   A[c][sxp] = feat[b, cgh*128+c, sy, sxp-4]  (bf16, zero pad cols 0-3/100-103), sy = y+4-kdy
//   M compact-banded: per 16-wide x-tile t, K-base kb = t<5 ? 16t : 72,
//   M_sh[x][sxp-kb(x)] = corr[b, kdy*9+(x+8-sxp), sy, sxp-4]; out-of-band zeroed once.
// R14: 128-ch blocks, 4 waves, 40.5KB LDS -> 3 blocks/CU; cgh-innermost dispatch so
// co-resident blocks share the same feat rows (disjoint channels) -> L2-bounded footprint.

#define RR 4
#define DD 9
#define D2 81
#define Bn 16
#define Cn 256
#define Hn 96
#define Wn 96
#define HWn (Hn*Wn)
#define NTH 256
#define NCB 128           // channels per block
#define KW  104           // A row width (ushort); 208 B stride
#define MW  36            // M compact window; 72 B stride

typedef __attribute__((ext_vector_type(8))) short bf16x8;
typedef __attribute__((ext_vector_type(4))) float f32x4;

__device__ __forceinline__ uint cvt_pk(float lo, float hi) {   // 2xf32 -> packed bf16
    uint r;
    asm("v_cvt_pk_bf16_f32 %0, %1, %2" : "=v"(r) : "v"(lo), "v"(hi));
    return r;
}
__device__ __forceinline__ ushort f2bf(float f) {
    uint u = __float_as_uint(f);
    return (ushort)((u + 0x7FFFu + ((u >> 16) & 1u)) >> 16);
}

__global__ __launch_bounds__(NTH, 4)
void corrT14_kernel(const float* __restrict__ corr,
                    const float* __restrict__ feat,
                    float* __restrict__ out)
{
    __shared__ ushort A_sh[NCB][KW];       // 26624 B, single buffer
    __shared__ ushort M_sh[2][Wn][MW];     // 13824 B, double buffer

    // XCD-chunked dispatch, cgh innermost -> CU-co-resident blocks share feat rows.
    // grid 3072 = 8 xcd * 384; per chunk: cgh(2) * y(96) * b-sub(2)
    int bid   = blockIdx.x;
    int xcd   = bid & 7;
    int local = bid >> 3;                  // 0..383
    int cgh   = local & 1;
    int r2    = local >> 1;                // 0..191
    int y     = r2 % Hn;
    int b     = xcd * 2 + r2 / Hn;

    const int tid  = threadIdx.x;
    const int lane = tid & 63;
    const int wid  = tid >> 6;            // wave -> 32-channel strip (of 128)
    const int mrow = lane & 15;
    const int kq   = lane >> 4;
    const int kgrp = kq << 3;             // K sub-base 0,8,16,24

    // zero once: A pads + all of M (out-of-band slots stay 0 forever)
    for (int i = tid; i < NCB; i += NTH) {
        *reinterpret_cast<uint2*>(&A_sh[i][0])   = make_uint2(0u, 0u);
        *reinterpret_cast<uint2*>(&A_sh[i][100]) = make_uint2(0u, 0u);
    }
    for (int i = tid; i < (int)(sizeof(M_sh) / 4); i += NTH) ((uint*)M_sh)[i] = 0u;
    __syncthreads();

    const int klo = max(0, y - (Hn - 1 - RR));   // valid kdy: sy = y+4-kdy in [0,96)
    const int khi = min(DD - 1, y + RR);

    const int ac  = tid >> 1;            // A staging: 2 threads per channel row (0..127)
    const int seg = tid & 1;             // 48-float half row
    const float* fbase = feat + (((size_t)b * Cn + cgh * NCB + ac) * Hn) * Wn + seg * 48;

    // ---- prologue: stage A + M for kdy = klo ----
    {
        const int sy = y + RR - klo;
        const float* src = fbase + (size_t)sy * Wn;
        #pragma unroll
        for (int i = 0; i < 12; ++i) {
            float4 v = *reinterpret_cast<const float4*>(src + i * 4);
            *reinterpret_cast<uint2*>(&A_sh[ac][4 + seg * 48 + i * 4])
                = make_uint2(cvt_pk(v.x, v.y), cvt_pk(v.z, v.w));
        }
        for (int t = tid; t < DD * Wn; t += NTH) {
            int kdx = t / Wn, x = t - kdx * Wn;
            int sxp = x + 2 * RR - kdx;
            int kbx = (x >= 80) ? 72 : (x & ~15);
            int sxc = min(max(sxp - RR, 0), Wn - 1);    // OOB value hits zeroed A pad
            M_sh[0][x][sxp - kbx] = f2bf(corr[((size_t)b * D2 + klo * DD + kdx) * HWn + sy * Wn + sxc]);
        }
    }
    __syncthreads();

    f32x4 acc[2][6];
    #pragma unroll
    for (int ct = 0; ct < 2; ++ct)
        #pragma unroll
        for (int t6 = 0; t6 < 6; ++t6)
            acc[ct][t6] = (f32x4){0.f, 0.f, 0.f, 0.f};

    #pragma unroll 1
    for (int kk = klo; kk <= khi; ++kk) {
        const int pb = (kk - klo) & 1;
        const bool vn = (kk + 1 <= khi);              // block-uniform
        const float* srcn = fbase + (size_t)(y + RR - (kk + 1)) * Wn;

        // -- T14 issue-early: half of next A row + next M scalars (regs across MFMA) --
        float4 fv0, fv1, fv2, fv3, fv4, fv5;
        float mv0 = 0.f, mv1 = 0.f, mv2 = 0.f, mv3 = 0.f;
        if (vn) {
            fv0 = *reinterpret_cast<const float4*>(srcn);
            fv1 = *reinterpret_cast<const float4*>(srcn + 4);
            fv2 = *reinterpret_cast<const float4*>(srcn + 8);
            fv3 = *reinterpret_cast<const float4*>(srcn + 12);
            fv4 = *reinterpret_cast<const float4*>(srcn + 16);
            fv5 = *reinterpret_cast<const float4*>(srcn + 20);
            const int syn = y + RR - (kk + 1);
            const float* cbn = corr + ((size_t)b * D2 + (kk + 1) * DD) * HWn + (size_t)syn * Wn;
            {
                int t = tid, kdx = t / Wn, x = t - kdx * Wn;
                int sxc = min(max(x + RR - kdx, 0), Wn - 1);
                mv0 = cbn[(size_t)kdx * HWn + sxc];
            }
            {
                int t = tid + NTH, kdx = t / Wn, x = t - kdx * Wn;
                int sxc = min(max(x + RR - kdx, 0), Wn - 1);
                mv1 = cbn[(size_t)kdx * HWn + sxc];
            }
            {
                int t = tid + 2 * NTH, kdx = t / Wn, x = t - kdx * Wn;
                int sxc = min(max(x + RR - kdx, 0), Wn - 1);
                mv2 = cbn[(size_t)kdx * HWn + sxc];
            }
            if (tid + 3 * NTH < DD * Wn) {
                int t = tid + 3 * NTH, kdx = t / Wn, x = t - kdx * Wn;
                int sxc = min(max(x + RR - kdx, 0), Wn - 1);
                mv3 = cbn[(size_t)kdx * HWn + sxc];
            }
        }

        // -- MFMA phase: 12 x v_mfma_f32_16x16x32_bf16 per wave --
        #pragma unroll
        for (int t6 = 0; t6 < 6; ++t6) {
            const int kb = (t6 == 5) ? 72 : t6 * 16;
            const ushort* mp = &M_sh[pb][t6 * 16 + mrow][kgrp];
            uint2 m0 = *reinterpret_cast<const uint2*>(mp);
            uint2 m1 = *reinterpret_cast<const uint2*>(mp + 4);
            uint4 bw = make_uint4(m0.x, m0.y, m1.x, m1.y);
            bf16x8 bfr = *reinterpret_cast<bf16x8*>(&bw);
            #pragma unroll
            for (int ct = 0; ct < 2; ++ct) {
                bf16x8 afr = *reinterpret_cast<const bf16x8*>(&A_sh[wid * 32 + ct * 16 + mrow][kb + kgrp]);
                acc[ct][t6] = __builtin_amdgcn_mfma_f32_16x16x32_bf16(afr, bfr, acc[ct][t6], 0, 0, 0);
            }
        }
        __syncthreads();                               // all waves done reading A_sh/M_sh[pb]

        // -- write-late: prefetched half, then direct half, then M --
        if (vn) {
            *reinterpret_cast<uint2*>(&A_sh[ac][4 + seg * 48 + 0])  = make_uint2(cvt_pk(fv0.x, fv0.y), cvt_pk(fv0.z, fv0.w));
            *reinterpret_cast<uint2*>(&A_sh[ac][4 + seg * 48 + 4])  = make_uint2(cvt_pk(fv1.x, fv1.y), cvt_pk(fv1.z, fv1.w));
            *reinterpret_cast<uint2*>(&A_sh[ac][4 + seg * 48 + 8])  = make_uint2(cvt_pk(fv2.x, fv2.y), cvt_pk(fv2.z, fv2.w));
            *reinterpret_cast<uint2*>(&A_sh[ac][4 + seg * 48 + 12]) = make_uint2(cvt_pk(fv3.x, fv3.y), cvt_pk(fv3.z, fv3.w));
            *reinterpret_cast<uint2*>(&A_sh[ac][4 + seg * 48 + 16]) = make_uint2(cvt_pk(fv4.x, fv4.y), cvt_pk(fv4.z, fv4.w));
            *reinterpret_cast<uint2*>(&A_sh[ac][4 + seg * 48 + 20]) = make_uint2(cvt_pk(fv5.x, fv5.y), cvt_pk(fv5.z, fv5.w));
            #pragma unroll
            for (int i = 6; i < 12; ++i) {
                float4 v = *reinterpret_cast<const float4*>(srcn + i * 4);
                *reinterpret_cast<uint2*>(&A_sh[ac][4 + seg * 48 + i * 4])
                    = make_uint2(cvt_pk(v.x, v.y), cvt_pk(v.z, v.w));
            }
            {
                int t = tid, kdx = t / Wn, x = t - kdx * Wn;
                int sxp = x + 2 * RR - kdx;
                int kbx = (x >= 80) ? 72 : (x & ~15);
                M_sh[pb ^ 1][x][sxp - kbx] = f2bf(mv0);
            }
            {
                int t = tid + NTH, kdx = t / Wn, x = t - kdx * Wn;
                int sxp = x + 2 * RR - kdx;
                int kbx = (x >= 80) ? 72 : (x & ~15);
                M_sh[pb ^ 1][x][sxp - kbx] = f2bf(mv1);
            }
            {
                int t = tid + 2 * NTH, kdx = t / Wn, x = t - kdx * Wn;
                int sxp = x + 2 * RR - kdx;
                int kbx = (x >= 80) ? 72 : (x & ~15);
                M_sh[pb ^ 1][x][sxp - kbx] = f2bf(mv2);
            }
            if (tid + 3 * NTH < DD * Wn) {
                int t = tid + 3 * NTH, kdx = t / Wn, x = t - kdx * Wn;
                int sxp = x + 2 * RR - kdx;
                int kbx = (x >= 80) ? 72 : (x & ~15);
                M_sh[pb ^ 1][x][sxp - kbx] = f2bf(mv3);
            }
        }
        __syncthreads();                               // buffers for kk+1 ready
    }

    // ---- epilogue: C/D layout col=lane&15 (x), row=(lane>>4)*4+r (c) — R11-verified ----
    const int csub = kq << 2;
    #pragma unroll
    for (int ct = 0; ct < 2; ++ct)
        #pragma unroll
        for (int t6 = 0; t6 < 6; ++t6)
            #pragma unroll
            for (int r = 0; r < 4; ++r)
                out[(((size_t)b * Cn + cgh * NCB + wid * 32 + ct * 16 + csub + r) * Hn + y) * Wn + t6 * 16 + mrow]
                    = acc[ct][t6][r];
}

extern "C" void kernel_launch(void* const* d_in, const int* in_sizes, int n_in,
                              void* d_out, int out_size, void* d_ws, size_t ws_size,
                              hipStream_t stream)
{
    const float* corr = (const float*)d_in[0];   // [16,81,96,96]
    const float* feat = (const float*)d_in[1];   // [16,256,96,96]
    float* out = (float*)d_out;                  // [16,256,96,96]

    const int grid = Bn * Hn * 2;                // 3072 blocks: (b, y, ch-half)
    corrT14_kernel<<<grid, NTH, 0, stream>>>(corr, feat, out);
}

// Round 15
// 215.949 us; speedup vs baseline: 1.5042x; 1.5042x over previous
//
#include <hip/hip_runtime.h>

// out[b,c,y,x] = sum_{kdy,kdx in [0,9)} corr[b, kdy*9+kdx, y+4-kdy, x+4-kdx] * feat[b,c, y+4-kdy, x+4-kdx]
// MFMA formulation (R11-verified numerics): per (b,y): out[C,X] = sum_kdy A[C,K] * M[K,X]
//   A_sh[c][sxp] = feat[b,c,sy,sxp-4] bf16 (pads 0-3/100-103 zero), sy = y+4-kdy
//   per 16-wide x-tile t: K-base kb = t<5 ? 16t : 72; window o = sxp-kb in [0,32)
//   M[x][o] = corr[b, kdy*9+(x+8-(kb+o)), sy, kb+o-4]  (0 out-of-band)
// R15: prepass1 feat->bf16 (halves 9x-restaged bytes + L2 footprint; kills in-loop cvt),
//      prepass2 corr->banded M in ws (each slice consumed exactly once; coalesced loads),
//      main: 64KB LDS -> 2 blocks/CU, T14 issue-early/write-late on A and M.

#define RR 4
#define DD 9
#define D2 81
#define Bn 16
#define Cn 256
#define Hn 96
#define Wn 96
#define HWn (Hn*Wn)
#define NTH 512
#define KW  104           // A row width (ushort); 208 B stride; frag cols mult-of-8 -> 16B aligned
#define MW  32            // M window width; 64 B stride -> all b128 aligned, 2-way banks (free)

typedef __attribute__((ext_vector_type(8))) short bf16x8;
typedef __attribute__((ext_vector_type(4))) float f32x4;

__device__ __forceinline__ uint cvt_pk(float lo, float hi) {   // 2xf32 -> packed bf16 (RNE)
    uint r;
    asm("v_cvt_pk_bf16_f32 %0, %1, %2" : "=v"(r) : "v"(lo), "v"(hi));
    return r;
}
__device__ __forceinline__ ushort f2bf(float f) {
    uint u = __float_as_uint(f);
    return (ushort)((u + 0x7FFFu + ((u >> 16) & 1u)) >> 16);
}

// ---- prepass 1: feat fp32 -> bf16 (151 MB read, 75.5 MB write) ----
__global__ void prep_feat_kernel(const float* __restrict__ feat, ushort* __restrict__ featb)
{
    const int n8 = Bn * Cn * HWn / 8;        // 4,718,592 groups of 8 floats
    const float4* src = reinterpret_cast<const float4*>(feat);
    uint4* dst = reinterpret_cast<uint4*>(featb);
    for (int i = blockIdx.x * blockDim.x + threadIdx.x; i < n8; i += gridDim.x * blockDim.x) {
        float4 a = src[2 * i], c = src[2 * i + 1];
        dst[i] = make_uint4(cvt_pk(a.x, a.y), cvt_pk(a.z, a.w), cvt_pk(c.x, c.y), cvt_pk(c.z, c.w));
    }
}

// ---- prepass 2: corr -> banded M slices [b][sy][kdy][x][MW] bf16 (85 MB write) ----
__global__ void prep_mband_kernel(const float* __restrict__ corr, ushort* __restrict__ mband)
{
    int s   = blockIdx.x;                    // ((b*Hn+sy)*DD + kdy)
    int kdy = s % DD; int r = s / DD;
    int sy  = r % Hn; int b = r / Hn;
    const float* cb = corr + ((size_t)b * D2 + kdy * DD) * HWn + (size_t)sy * Wn;
    ushort* mb = mband + (size_t)s * (Wn * MW);
    for (int e = threadIdx.x; e < Wn * MW; e += blockDim.x) {
        int x = e >> 5, o = e & 31;
        int kb  = (x >= 80) ? 72 : (x & ~15);
        int sxp = kb + o;
        int kdx = x + 2 * RR - sxp;
        float v = 0.f;
        if (kdx >= 0 && kdx < DD && sxp >= RR && sxp < Wn + RR)
            v = cb[(size_t)kdx * HWn + (sxp - RR)];
        mb[e] = f2bf(v);
    }
}

// ---- main kernel. MODE 0: no ws; 1: featb; 2: featb + mband ----
template<int MODE>
__global__ __launch_bounds__(NTH, 2)
void corrT15_kernel(const float* __restrict__ corr,
                    const float* __restrict__ feat,
                    const ushort* __restrict__ featb,
                    const ushort* __restrict__ mband,
                    float* __restrict__ out)
{
    __shared__ ushort A_sh[Cn][KW];        // 53248 B, single buffer
    __shared__ ushort M_sh[2][Wn][MW];     // 12288 B, double buffer  (total 64 KB -> 2 blocks/CU)

    // XCD-chunked dispatch: y contiguous per XCD (grid 1536 = 8*192)
    int bid = blockIdx.x;
    int L   = (bid & 7) * 192 + (bid >> 3);
    int y   = L % Hn;
    int b   = L / Hn;

    const int tid  = threadIdx.x;
    const int lane = tid & 63;
    const int wid  = tid >> 6;
    const int mrow = lane & 15;
    const int kq   = lane >> 4;
    const int kgrp = kq << 3;

    // zero once: A pads; (MODE<2) M buffers — in-band slots rewritten each step, rest stay 0
    for (int i = tid; i < Cn; i += NTH) {
        *reinterpret_cast<uint2*>(&A_sh[i][0])   = make_uint2(0u, 0u);
        *reinterpret_cast<uint2*>(&A_sh[i][100]) = make_uint2(0u, 0u);
    }
    if (MODE < 2)
        for (int i = tid; i < (int)(sizeof(M_sh) / 4); i += NTH) ((uint*)M_sh)[i] = 0u;
    __syncthreads();

    const int klo = max(0, y - (Hn - 1 - RR));
    const int khi = min(DD - 1, y + RR);

    const int ac  = tid >> 1;             // 2 threads per channel row
    const int seg = tid & 1;              // 48-element half row
    const ushort* fb_base = featb + (((size_t)b * Cn + ac) * Hn) * (size_t)Wn + seg * 48;
    const float*  ff_base = feat  + (((size_t)b * Cn + ac) * Hn) * (size_t)Wn + seg * 48;

    // ---- prologue: stage A + M for kdy = klo ----
    {
        const int sy = y + RR - klo;
        if constexpr (MODE >= 1) {
            const uint4* src = reinterpret_cast<const uint4*>(fb_base + (size_t)sy * Wn);
            #pragma unroll
            for (int i = 0; i < 6; ++i) {
                uint4 v = src[i];
                uint2* d = reinterpret_cast<uint2*>(&A_sh[ac][4 + seg * 48 + i * 8]);
                d[0] = make_uint2(v.x, v.y);
                d[1] = make_uint2(v.z, v.w);
            }
        } else {
            const float* src = ff_base + (size_t)sy * Wn;
            #pragma unroll
            for (int i = 0; i < 12; ++i) {
                float4 v = *reinterpret_cast<const float4*>(src + i * 4);
                *reinterpret_cast<uint2*>(&A_sh[ac][4 + seg * 48 + i * 4])
                    = make_uint2(cvt_pk(v.x, v.y), cvt_pk(v.z, v.w));
            }
        }
        if constexpr (MODE == 2) {
            const ushort* ms = mband + (((size_t)b * Hn + sy) * DD + klo) * (size_t)(Wn * MW);
            if (tid < 384)
                reinterpret_cast<uint4*>(&M_sh[0][0][0])[tid] = reinterpret_cast<const uint4*>(ms)[tid];
        } else {
            for (int t = tid; t < DD * Wn; t += NTH) {
                int kdx = t / Wn, x = t - kdx * Wn;
                int sxp = x + 2 * RR - kdx;
                int kb  = (x >= 80) ? 72 : (x & ~15);
                int sxc = min(max(sxp - RR, 0), Wn - 1);
                M_sh[0][x][sxp - kb] = f2bf(corr[((size_t)b * D2 + klo * DD + kdx) * HWn + (size_t)sy * Wn + sxc]);
            }
        }
    }
    __syncthreads();

    f32x4 acc[2][6];
    #pragma unroll
    for (int ct = 0; ct < 2; ++ct)
        #pragma unroll
        for (int t6 = 0; t6 < 6; ++t6)
            acc[ct][t6] = (f32x4){0.f, 0.f, 0.f, 0.f};

    #pragma unroll 1
    for (int kk = klo; kk <= khi; ++kk) {
        const int pb = (kk - klo) & 1;
        const bool vn = (kk + 1 <= khi);
        const int syn = y + RR - (kk + 1);

        // -- T14 issue-early: next A row + next M slice held in regs across MFMA --
        uint4 a0, a1, a2, a3, a4, a5;
        float4 g0, g1, g2, g3, g4, g5;
        uint4 mvv = make_uint4(0u, 0u, 0u, 0u);
        float mv0 = 0.f, mv1 = 0.f;
        if (vn) {
            if constexpr (MODE >= 1) {
                const uint4* src = reinterpret_cast<const uint4*>(fb_base + (size_t)syn * Wn);
                a0 = src[0]; a1 = src[1]; a2 = src[2]; a3 = src[3]; a4 = src[4]; a5 = src[5];
            } else {
                const float* src = ff_base + (size_t)syn * Wn;
                g0 = *reinterpret_cast<const float4*>(src);
                g1 = *reinterpret_cast<const float4*>(src + 4);
                g2 = *reinterpret_cast<const float4*>(src + 8);
                g3 = *reinterpret_cast<const float4*>(src + 12);
                g4 = *reinterpret_cast<const float4*>(src + 16);
                g5 = *reinterpret_cast<const float4*>(src + 20);
            }
            if constexpr (MODE == 2) {
                const ushort* ms = mband + (((size_t)b * Hn + syn) * DD + (kk + 1)) * (size_t)(Wn * MW);
                if (tid < 384) mvv = reinterpret_cast<const uint4*>(ms)[tid];
            } else {
                {
                    int t = tid, kdx = t / Wn, x = t - kdx * Wn;
                    int sxc = min(max(x + RR - kdx, 0), Wn - 1);
                    mv0 = corr[((size_t)b * D2 + (kk + 1) * DD + kdx) * HWn + (size_t)syn * Wn + sxc];
                }
                if (tid + NTH < DD * Wn) {
                    int t = tid + NTH, kdx = t / Wn, x = t - kdx * Wn;
                    int sxc = min(max(x + RR - kdx, 0), Wn - 1);
                    mv1 = corr[((size_t)b * D2 + (kk + 1) * DD + kdx) * HWn + (size_t)syn * Wn + sxc];
                }
            }
        }

        // -- MFMA phase: 12 x v_mfma_f32_16x16x32_bf16 per wave --
        #pragma unroll
        for (int t6 = 0; t6 < 6; ++t6) {
            const int kb = (t6 == 5) ? 72 : t6 * 16;
            uint4 bw = *reinterpret_cast<const uint4*>(&M_sh[pb][t6 * 16 + mrow][kgrp]);
            bf16x8 bfr = *reinterpret_cast<bf16x8*>(&bw);
            #pragma unroll
            for (int ct = 0; ct < 2; ++ct) {
                bf16x8 afr = *reinterpret_cast<const bf16x8*>(&A_sh[wid * 32 + ct * 16 + mrow][kb + kgrp]);
                acc[ct][t6] = __builtin_amdgcn_mfma_f32_16x16x32_bf16(afr, bfr, acc[ct][t6], 0, 0, 0);
            }
        }
        __syncthreads();                  // done reading A_sh / M_sh[pb]

        // -- write-late --
        if (vn) {
            if constexpr (MODE >= 1) {
                uint2* d0 = reinterpret_cast<uint2*>(&A_sh[ac][4 + seg * 48]);
                d0[0] = make_uint2(a0.x, a0.y); d0[1] = make_uint2(a0.z, a0.w);
                d0[2] = make_uint2(a1.x, a1.y); d0[3] = make_uint2(a1.z, a1.w);
                d0[4] = make_uint2(a2.x, a2.y); d0[5] = make_uint2(a2.z, a2.w);
                d0[6] = make_uint2(a3.x, a3.y); d0[7] = make_uint2(a3.z, a3.w);
                d0[8] = make_uint2(a4.x, a4.y); d0[9] = make_uint2(a4.z, a4.w);
                d0[10] = make_uint2(a5.x, a5.y); d0[11] = make_uint2(a5.z, a5.w);
            } else {
                *reinterpret_cast<uint2*>(&A_sh[ac][4 + seg * 48 + 0])  = make_uint2(cvt_pk(g0.x, g0.y), cvt_pk(g0.z, g0.w));
                *reinterpret_cast<uint2*>(&A_sh[ac][4 + seg * 48 + 4])  = make_uint2(cvt_pk(g1.x, g1.y), cvt_pk(g1.z, g1.w));
                *reinterpret_cast<uint2*>(&A_sh[ac][4 + seg * 48 + 8])  = make_uint2(cvt_pk(g2.x, g2.y), cvt_pk(g2.z, g2.w));
                *reinterpret_cast<uint2*>(&A_sh[ac][4 + seg * 48 + 12]) = make_uint2(cvt_pk(g3.x, g3.y), cvt_pk(g3.z, g3.w));
                *reinterpret_cast<uint2*>(&A_sh[ac][4 + seg * 48 + 16]) = make_uint2(cvt_pk(g4.x, g4.y), cvt_pk(g4.z, g4.w));
                *reinterpret_cast<uint2*>(&A_sh[ac][4 + seg * 48 + 20]) = make_uint2(cvt_pk(g5.x, g5.y), cvt_pk(g5.z, g5.w));
                const float* src = ff_base + (size_t)syn * Wn;
                #pragma unroll
                for (int i = 6; i < 12; ++i) {
                    float4 v = *reinterpret_cast<const float4*>(src + i * 4);
                    *reinterpret_cast<uint2*>(&A_sh[ac][4 + seg * 48 + i * 4])
                        = make_uint2(cvt_pk(v.x, v.y), cvt_pk(v.z, v.w));
                }
            }
            if constexpr (MODE == 2) {
                if (tid < 384)
                    reinterpret_cast<uint4*>(&M_sh[pb ^ 1][0][0])[tid] = mvv;
            } else {
                {
                    int t = tid, kdx = t / Wn, x = t - kdx * Wn;
                    int sxp = x + 2 * RR - kdx;
                    int kb  = (x >= 80) ? 72 : (x & ~15);
                    M_sh[pb ^ 1][x][sxp - kb] = f2bf(mv0);
                }
                if (tid + NTH < DD * Wn) {
                    int t = tid + NTH, kdx = t / Wn, x = t - kdx * Wn;
                    int sxp = x + 2 * RR - kdx;
                    int kb  = (x >= 80) ? 72 : (x & ~15);
                    M_sh[pb ^ 1][x][sxp - kb] = f2bf(mv1);
                }
            }
        }
        __syncthreads();
    }

    // ---- epilogue: C/D layout col=lane&15 (x), row=(lane>>4)*4+r (c) — R11-verified ----
    const int csub = kq << 2;
    #pragma unroll
    for (int ct = 0; ct < 2; ++ct)
        #pragma unroll
        for (int t6 = 0; t6 < 6; ++t6)
            #pragma unroll
            for (int r = 0; r < 4; ++r)
                out[(((size_t)b * Cn + wid * 32 + ct * 16 + csub + r) * Hn + y) * Wn + t6 * 16 + mrow]
                    = acc[ct][t6][r];
}

extern "C" void kernel_launch(void* const* d_in, const int* in_sizes, int n_in,
                              void* d_out, int out_size, void* d_ws, size_t ws_size,
                              hipStream_t stream)
{
    const float* corr = (const float*)d_in[0];   // [16,81,96,96]
    const float* feat = (const float*)d_in[1];   // [16,256,96,96]
    float* out = (float*)d_out;                  // [16,256,96,96]

    const size_t needF = (size_t)Bn * Cn * HWn * 2;            // 75,497,472
    const size_t needM = (size_t)Bn * Hn * DD * Wn * MW * 2;   // 84,934,656
    int mode = 0;
    if (ws_size >= needF + needM) mode = 2;
    else if (ws_size >= needF)    mode = 1;

    ushort* featb = (ushort*)d_ws;
    ushort* mband = (ushort*)((char*)d_ws + needF);

    if (mode >= 1) prep_feat_kernel<<<2048, 256, 0, stream>>>(feat, featb);
    if (mode == 2) prep_mband_kernel<<<Bn * Hn * DD, 256, 0, stream>>>(corr, mband);

    const int grid = Bn * Hn;                    // 1536 blocks: one (b,y) each
    if (mode == 2)      corrT15_kernel<2><<<grid, NTH, 0, stream>>>(corr, feat, featb, mband, out);
    else if (mode == 1) corrT15_kernel<1><<<grid, NTH, 0, stream>>>(corr, feat, featb, mband, out);
    else                corrT15_kernel<0><<<grid, NTH, 0, stream>>>(corr, feat, featb, mband, out);
}